// Round 2
// baseline (4999.079 us; speedup 1.0000x reference)
//
#include <hip/hip_runtime.h>
#include <stdint.h>

#define D 512
#define BATCH 32
#define TT 2048
#define BT (BATCH*TT)   // 65536

typedef unsigned short u16;
typedef __attribute__((ext_vector_type(8))) short bf16x8;
typedef __attribute__((ext_vector_type(4))) float f32x4;
typedef __attribute__((ext_vector_type(4))) int i32x4;

__device__ __forceinline__ float bf2f(u16 u){
  union { unsigned int i; float f; } v; v.i = ((unsigned int)u) << 16; return v.f;
}
__device__ __forceinline__ u16 f2bf(float f){
  union { float f; unsigned int i; } v; v.f = f;
  unsigned int r = (v.i + 0x7fffu + ((v.i >> 16) & 1u)) >> 16;
  return (u16)r;
}

// ---------------- rmsnorm: xn = x/max(||x||,1e-12) * sqrt(D) * (gamma+1) ---
// x fp32 -> xn bf16 plane
__global__ __launch_bounds__(256) void rmsnorm_k(const float* __restrict__ x,
                                                 const float* __restrict__ gamma,
                                                 u16* __restrict__ xn){
  int row = blockIdx.x;
  int t = threadIdx.x;
  const float* xr = x + (size_t)row * D;
  float v0 = xr[t];
  float v1 = xr[t + 256];
  float s = v0*v0 + v1*v1;
  #pragma unroll
  for (int o = 32; o > 0; o >>= 1) s += __shfl_down(s, o);
  __shared__ float red[4];
  int lane = t & 63, wv = t >> 6;
  if (lane == 0) red[wv] = s;
  __syncthreads();
  float tot = red[0] + red[1] + red[2] + red[3];
  float n = fmaxf(sqrtf(tot), 1e-12f);
  float sc = 22.627416997969522f / n;   // sqrt(512)
  u16* o_ = xn + (size_t)row * D;
  o_[t]       = f2bf(v0 * sc * (gamma[t] + 1.f));
  o_[t + 256] = f2bf(v1 * sc * (gamma[t + 256] + 1.f));
}

// -------- 512x512 transpose + fp32->bf16 convert (dst[n][k] = src[k][n]) ---
__global__ __launch_bounds__(256) void transpose_k(const float* __restrict__ src,
                                                   u16* __restrict__ dst){
  __shared__ u16 tile[32][33];
  int bx = blockIdx.x * 32, by = blockIdx.y * 32;
  int tx = threadIdx.x & 31, ty = threadIdx.x >> 5;   // 32 x 8
  #pragma unroll
  for (int i = 0; i < 32; i += 8)
    tile[ty + i][tx] = f2bf(src[(size_t)(by + ty + i) * D + bx + tx]);
  __syncthreads();
  #pragma unroll
  for (int i = 0; i < 32; i += 8)
    dst[(size_t)(bx + ty + i) * D + by + tx] = tile[tx][ty + i];
}

// -------- per-column int8 quantization of Whf (fp32 in) -------------------
// Wq[e*128 + w] packs k = 4w..4w+3 of column e (byte 0 = lowest k).
__global__ __launch_bounds__(64) void quant_col_k(const float* __restrict__ W,
                                                  int* __restrict__ Wq,
                                                  float* __restrict__ sc){
  int e = blockIdx.x;        // column index
  int lane = threadIdx.x;    // 64 lanes, each covers 8 d's
  float w[8];
  float m = 0.f;
  #pragma unroll
  for (int j = 0; j < 8; j++){
    w[j] = W[(size_t)(lane*8 + j) * D + e];
    m = fmaxf(m, fabsf(w[j]));
  }
  #pragma unroll
  for (int o = 32; o > 0; o >>= 1) m = fmaxf(m, __shfl_xor(m, o));
  float inv = (m > 0.f) ? (127.f / m) : 0.f;
  int q[8];
  #pragma unroll
  for (int j = 0; j < 8; j++){
    int v = __float2int_rn(w[j] * inv);
    v = v < -127 ? -127 : (v > 127 ? 127 : v);
    q[j] = v & 0xff;
  }
  int p0 = q[0] | (q[1] << 8) | (q[2] << 16) | (q[3] << 24);
  int p1 = q[4] | (q[5] << 8) | (q[6] << 16) | (q[7] << 24);
  Wq[e*128 + lane*2]     = p0;
  Wq[e*128 + lane*2 + 1] = p1;
  if (lane == 0) sc[e] = m / (127.f * 127.f);
}

// ---------------- bf16 GEMM: C[m][n] = sum_k A[m][k]*Bt[n][k] -------------
__global__ __launch_bounds__(256) void gemm_bt_k(const u16* __restrict__ A,
                                                 const u16* __restrict__ Bt,
                                                 u16* __restrict__ C,
                                                 int do_tanh){
  __shared__ __align__(16) u16 As[128*32];
  __shared__ __align__(16) u16 Bs[128*32];
  int tid = threadIdx.x;
  int bm = blockIdx.x, bn = blockIdx.y;
  int wv = tid >> 6, lane = tid & 63;
  int wm = (wv & 1) * 64, wn = (wv >> 1) * 64;
  int m0 = lane & 15, quad = lane >> 4;
  f32x4 acc[4][4];
  #pragma unroll
  for (int i = 0; i < 4; i++)
    #pragma unroll
    for (int j = 0; j < 4; j++){
      f32x4 z = {0.f, 0.f, 0.f, 0.f};
      acc[i][j] = z;
    }
  const size_t arow = (size_t)bm * 128;
  const size_t brow = (size_t)bn * 128;
  for (int k0 = 0; k0 < D; k0 += 32){
    __syncthreads();
    #pragma unroll
    for (int i = 0; i < 2; i++){
      int c = tid + 256*i;
      int r = c >> 2, ko = (c & 3) * 8;
      ((int4*)As)[c] = *(const int4*)(A  + (arow + r) * D + k0 + ko);
      ((int4*)Bs)[c] = *(const int4*)(Bt + (brow + r) * D + k0 + ko);
    }
    __syncthreads();
    bf16x8 af[4], bfr[4];
    #pragma unroll
    for (int i = 0; i < 4; i++){
      af[i]  = *(const bf16x8*)(As + (wm + i*16 + m0) * 32 + quad*8);
      bfr[i] = *(const bf16x8*)(Bs + (wn + i*16 + m0) * 32 + quad*8);
    }
    #pragma unroll
    for (int i = 0; i < 4; i++)
      #pragma unroll
      for (int j = 0; j < 4; j++)
        acc[i][j] = __builtin_amdgcn_mfma_f32_16x16x32_bf16(af[i], bfr[j], acc[i][j], 0, 0, 0);
  }
  #pragma unroll
  for (int i = 0; i < 4; i++)
    #pragma unroll
    for (int j = 0; j < 4; j++)
      #pragma unroll
      for (int r = 0; r < 4; r++){
        size_t row = arow + wm + i*16 + quad*4 + r;
        int col = bn*128 + wn + j*16 + m0;
        float v = acc[i][j][r];
        if (do_tanh) v = tanhf(v);
        C[row * D + col] = f2bf(v);
      }
}

// ---------------- sequential LRU scan, one block per batch element --------
// The per-step matvec h @ Whf now runs on the MATRIX pipe:
//   mfma_i32_16x16x64_i8 with h replicated across the 16 M-rows.
//   Weights are register-stationary B-fragments (32 x i32x4 per lane),
//   loaded ONCE from the per-column Wq packing (frag = int4 at
//   Wq[e*128 + c*16 + grp*4] -- no repacking needed).
//   Per-step LDS traffic: 8 ds_read_b128 per wave (64 KiB/step/CU) vs the
//   old 256 KiB/step broadcast -- the mfma operand network does the fanout.
// Integer accumulation is exact => z identical to the sdot4 version.
// Wave w owns output dims [w*64, w*64+64); lane l owns e = w*64 + l.
// C-layout col = lane&15 (dtype-independent), rows are replicated h copies,
// so lane l reads tile (l>>4), element 0.
__global__ __launch_bounds__(512, 2) void lru_scan_k(u16* __restrict__ Nn,        // tanh(x@Wn), becomes H
                                                     const u16* __restrict__ Ff,  // x@Wif
                                                     const int* __restrict__ Wq,
                                                     const float* __restrict__ sc,
                                                     const float* __restrict__ bhf){
  int tid = threadIdx.x;
  int b = blockIdx.x;
  int wv  = tid >> 6;        // wave 0..7
  int l   = tid & 63;
  int grp = l >> 4;          // k-group (16 bytes each) within fragments
  int col = l & 15;
  int e   = wv * 64 + l;     // output dim this lane owns in the epilogue

  // B-fragments: bf[j][c] supplies B[k = c*64 + grp*16 + i][n = wv*64 + j*16 + col]
  i32x4 bf[4][8];
  #pragma unroll
  for (int j = 0; j < 4; j++){
    const int* wp = Wq + (wv*64 + j*16 + col) * 128;
    #pragma unroll
    for (int c = 0; c < 8; c++)
      bf[j][c] = *(const i32x4*)(wp + c*16 + grp*4);
  }
  float scale = sc[e];
  float bias  = bhf[e];

  __shared__ __align__(16) char hq[2][512];
  if (tid < 128) ((int*)hq[0])[tid] = 0;
  float h = 0.f;
  const size_t base = (size_t)b * TT * D + e;
  u16* np = Nn + base;
  const u16* fp = Ff + base;
  float nv  = bf2f(np[0]);
  float fvb = bf2f(fp[0]) + bias;
  __syncthreads();

  for (int t = 0; t < TT; t++){
    float nv_n = 0.f, fvb_n = 0.f;
    if (t < TT - 1){
      nv_n  = bf2f(np[(size_t)(t+1) * D]);
      fvb_n = bf2f(fp[(size_t)(t+1) * D]) + bias;
    }
    const char* hb = hq[t & 1];
    i32x4 acc0 = {0,0,0,0}, acc1 = {0,0,0,0}, acc2 = {0,0,0,0}, acc3 = {0,0,0,0};
    #pragma unroll
    for (int c = 0; c < 8; c++){
      i32x4 a = *(const i32x4*)(hb + c*64 + grp*16);   // A-frag: h bytes k=c*64+grp*16..+15
      acc0 = __builtin_amdgcn_mfma_i32_16x16x64_i8(a, bf[0][c], acc0, 0, 0, 0);
      acc1 = __builtin_amdgcn_mfma_i32_16x16x64_i8(a, bf[1][c], acc1, 0, 0, 0);
      acc2 = __builtin_amdgcn_mfma_i32_16x16x64_i8(a, bf[2][c], acc2, 0, 0, 0);
      acc3 = __builtin_amdgcn_mfma_i32_16x16x64_i8(a, bf[3][c], acc3, 0, 0, 0);
    }
    // lane l's own column lives in tile (l>>4) at element 0 (any row valid)
    int z = (grp == 0) ? acc0[0] : (grp == 1) ? acc1[0] : (grp == 2) ? acc2[0] : acc3[0];
    float arg = (float)z * scale + fvb;
    float g = 1.f / (1.f + __expf(-arg));
    h = h + g * (nv - h);
    np[(size_t)t * D] = f2bf(h);          // overwrite Nn with H
    int q = __float2int_rn(h * 127.f);
    q = q < -127 ? -127 : (q > 127 ? 127 : q);
    hq[(t+1) & 1][e] = (char)q;
    nv = nv_n; fvb = fvb_n;
    // raw barrier: only drain LDS (the global h-store may stay in flight;
    // the compiler's counted vmcnt on the t+1 prefetch loads orders it)
    asm volatile("s_waitcnt lgkmcnt(0)\n\ts_barrier" ::: "memory");
  }
}

// ---------------- final gate_cell, pass 1: lru -> (in-place over Nng) -----
__global__ __launch_bounds__(256) void final1_k(const u16* __restrict__ xn,
                                                u16* __restrict__ Nng,        // tanh(h1@gWn), becomes lru
                                                const u16* __restrict__ Ffg,  // h1@gWif
                                                const u16* __restrict__ Ghf,  // xn@gWhf
                                                const float* __restrict__ gbhf){
  size_t i = (size_t)blockIdx.x * 256 + threadIdx.x;
  int e = (int)(i & (D - 1));
  float xnv = bf2f(xn[i]);
  float nv  = bf2f(Nng[i]);
  float arg = bf2f(Ghf[i]) + gbhf[e] + bf2f(Ffg[i]);
  float g = 1.f / (1.f + __expf(-arg));
  float lru = xnv + g * (nv - xnv);
  Nng[i] = f2bf(lru);
}

// ---------------- final pass 2: out = lru + x (fp32) ----------------------
__global__ __launch_bounds__(256) void final2_k(const u16* __restrict__ lru,
                                                const float* __restrict__ x,
                                                float* __restrict__ out){
  size_t i = (size_t)blockIdx.x * 256 + threadIdx.x;
  out[i] = bf2f(lru[i]) + x[i];
}

extern "C" void kernel_launch(void* const* d_in, const int* in_sizes, int n_in,
                              void* d_out, int out_size, void* d_ws, size_t ws_size,
                              hipStream_t stream){
  const float* x      = (const float*)d_in[0];
  const float* gamma  = (const float*)d_in[1];
  const float* g_Wn   = (const float*)d_in[2];
  const float* g_Wif  = (const float*)d_in[3];
  const float* g_Whf  = (const float*)d_in[4];
  const float* g_bhf  = (const float*)d_in[5];
  const float* l0_Wn  = (const float*)d_in[6];
  const float* l0_Wif = (const float*)d_in[7];
  const float* l0_Whf = (const float*)d_in[8];
  const float* l0_bhf = (const float*)d_in[9];
  const float* l1_Wn  = (const float*)d_in[10];
  const float* l1_Wif = (const float*)d_in[11];
  const float* l1_Whf = (const float*)d_in[12];
  const float* l1_bhf = (const float*)d_in[13];
  float* out = (float*)d_out;

  // ---- plane layout: P0,P1 in ws; P2,P3 inside d_out (2 bf16 planes = 134MB)
  char* ws = (char*)d_ws;
  const size_t PLANE = (size_t)BT * D * 2;      // 67.1 MB bf16 plane
  u16* P0 = (u16*)(ws);                         // xn (live to the end)
  u16* P1 = (u16*)(ws + PLANE);                 // Nn0/H0, then Nn_g, then lru
  u16* P2 = (u16*)d_out;                        // Ff planes
  u16* P3 = P2 + (size_t)BT * D;                // Nn1/H1, then Ghf

  char* wb = ws + 2*PLANE;
  const size_t WSZ = (size_t)D * D * 2;         // 512 KB per transposed bf16 weight
  u16* T_l0Wn  = (u16*)(wb + 0*WSZ);
  u16* T_l0Wif = (u16*)(wb + 1*WSZ);
  u16* T_gWhf  = (u16*)(wb + 2*WSZ);
  u16* T_l1Wn  = (u16*)(wb + 3*WSZ);
  u16* T_l1Wif = (u16*)(wb + 4*WSZ);
  u16* T_gWn   = (u16*)(wb + 5*WSZ);
  u16* T_gWif  = (u16*)(wb + 6*WSZ);
  int*   Wq0 = (int*)  (wb + 7*WSZ);
  int*   Wq1 = (int*)  (wb + 7*WSZ + (size_t)D*D);
  float* sc0 = (float*)(wb + 7*WSZ + 2*(size_t)D*D);
  float* sc1 = (float*)(wb + 7*WSZ + 2*(size_t)D*D + D*4);

  dim3 tb(256), tg(16, 16);
  // weight prep (tiny)
  transpose_k<<<tg, tb, 0, stream>>>(l0_Wn,  T_l0Wn);
  transpose_k<<<tg, tb, 0, stream>>>(l0_Wif, T_l0Wif);
  transpose_k<<<tg, tb, 0, stream>>>(g_Whf,  T_gWhf);
  transpose_k<<<tg, tb, 0, stream>>>(l1_Wn,  T_l1Wn);
  transpose_k<<<tg, tb, 0, stream>>>(l1_Wif, T_l1Wif);
  transpose_k<<<tg, tb, 0, stream>>>(g_Wn,   T_gWn);
  transpose_k<<<tg, tb, 0, stream>>>(g_Wif,  T_gWif);
  quant_col_k<<<512, 64, 0, stream>>>(l0_Whf, Wq0, sc0);
  quant_col_k<<<512, 64, 0, stream>>>(l1_Whf, Wq1, sc1);

  rmsnorm_k<<<BT, 256, 0, stream>>>(x, gamma, P0);

  dim3 gg(BT/128, D/128);
  // layer 0
  gemm_bt_k<<<gg, tb, 0, stream>>>(P0, T_l0Wn,  P1, 1);   // Nn0
  gemm_bt_k<<<gg, tb, 0, stream>>>(P0, T_l0Wif, P2, 0);   // Ff0
  lru_scan_k<<<BATCH, 512, 0, stream>>>(P1, P2, Wq0, sc0, l0_bhf);  // H0 -> P1
  // layer 1
  gemm_bt_k<<<gg, tb, 0, stream>>>(P1, T_l1Wn,  P3, 1);   // Nn1
  gemm_bt_k<<<gg, tb, 0, stream>>>(P1, T_l1Wif, P2, 0);   // Ff1
  lru_scan_k<<<BATCH, 512, 0, stream>>>(P3, P2, Wq1, sc1, l1_bhf);  // H1 -> P3
  // gate cell projections (H0 dead -> P1, Ff1 dead -> P2)
  gemm_bt_k<<<gg, tb, 0, stream>>>(P3, T_gWn,  P1, 1);    // Nn_g
  gemm_bt_k<<<gg, tb, 0, stream>>>(P3, T_gWif, P2, 0);    // Ff_g
  gemm_bt_k<<<gg, tb, 0, stream>>>(P0, T_gWhf, P3, 0);    // Ghf (H1 dead)

  final1_k<<<BT*D/256, 256, 0, stream>>>(P0, P1, P2, P3, g_bhf);  // lru -> P1
  final2_k<<<BT*D/256, 256, 0, stream>>>(P1, x, out);
}

// Round 3
// 4194.703 us; speedup vs baseline: 1.1918x; 1.1918x over previous
//
#include <hip/hip_runtime.h>
#include <stdint.h>

#define D 512
#define BATCH 32
#define TT 2048
#define BT (BATCH*TT)   // 65536

typedef unsigned short u16;
typedef __attribute__((ext_vector_type(8))) short bf16x8;
typedef __attribute__((ext_vector_type(4))) float f32x4;

__device__ __forceinline__ float bf2f(u16 u){
  union { unsigned int i; float f; } v; v.i = ((unsigned int)u) << 16; return v.f;
}
__device__ __forceinline__ u16 f2bf(float f){
  union { float f; unsigned int i; } v; v.f = f;
  unsigned int r = (v.i + 0x7fffu + ((v.i >> 16) & 1u)) >> 16;
  return (u16)r;
}

__device__ __forceinline__ int dot4i8(int a, int b, int c){
#if __has_builtin(__builtin_amdgcn_sdot4)
  return __builtin_amdgcn_sdot4(a, b, c, false);
#else
  c += (int)(char)(a      ) * (int)(char)(b      );
  c += (int)(char)(a >>  8) * (int)(char)(b >>  8);
  c += (int)(char)(a >> 16) * (int)(char)(b >> 16);
  c += (int)(char)(a >> 24) * (int)(char)(b >> 24);
  return c;
#endif
}

// ---------------- rmsnorm: xn = x/max(||x||,1e-12) * sqrt(D) * (gamma+1) ---
// x fp32 -> xn bf16 plane
__global__ __launch_bounds__(256) void rmsnorm_k(const float* __restrict__ x,
                                                 const float* __restrict__ gamma,
                                                 u16* __restrict__ xn){
  int row = blockIdx.x;
  int t = threadIdx.x;
  const float* xr = x + (size_t)row * D;
  float v0 = xr[t];
  float v1 = xr[t + 256];
  float s = v0*v0 + v1*v1;
  #pragma unroll
  for (int o = 32; o > 0; o >>= 1) s += __shfl_down(s, o);
  __shared__ float red[4];
  int lane = t & 63, wv = t >> 6;
  if (lane == 0) red[wv] = s;
  __syncthreads();
  float tot = red[0] + red[1] + red[2] + red[3];
  float n = fmaxf(sqrtf(tot), 1e-12f);
  float sc = 22.627416997969522f / n;   // sqrt(512)
  u16* o_ = xn + (size_t)row * D;
  o_[t]       = f2bf(v0 * sc * (gamma[t] + 1.f));
  o_[t + 256] = f2bf(v1 * sc * (gamma[t + 256] + 1.f));
}

// -------- 512x512 transpose + fp32->bf16 convert (dst[n][k] = src[k][n]) ---
__global__ __launch_bounds__(256) void transpose_k(const float* __restrict__ src,
                                                   u16* __restrict__ dst){
  __shared__ u16 tile[32][33];
  int bx = blockIdx.x * 32, by = blockIdx.y * 32;
  int tx = threadIdx.x & 31, ty = threadIdx.x >> 5;   // 32 x 8
  #pragma unroll
  for (int i = 0; i < 32; i += 8)
    tile[ty + i][tx] = f2bf(src[(size_t)(by + ty + i) * D + bx + tx]);
  __syncthreads();
  #pragma unroll
  for (int i = 0; i < 32; i += 8)
    dst[(size_t)(bx + ty + i) * D + by + tx] = tile[tx][ty + i];
}

// -------- per-column int8 quantization of Whf (fp32 in) -------------------
// Wq[e*128 + w] packs k = 4w..4w+3 of column e (byte 0 = lowest k).
__global__ __launch_bounds__(64) void quant_col_k(const float* __restrict__ W,
                                                  int* __restrict__ Wq,
                                                  float* __restrict__ sc){
  int e = blockIdx.x;        // column index
  int lane = threadIdx.x;    // 64 lanes, each covers 8 d's
  float w[8];
  float m = 0.f;
  #pragma unroll
  for (int j = 0; j < 8; j++){
    w[j] = W[(size_t)(lane*8 + j) * D + e];
    m = fmaxf(m, fabsf(w[j]));
  }
  #pragma unroll
  for (int o = 32; o > 0; o >>= 1) m = fmaxf(m, __shfl_xor(m, o));
  float inv = (m > 0.f) ? (127.f / m) : 0.f;
  int q[8];
  #pragma unroll
  for (int j = 0; j < 8; j++){
    int v = __float2int_rn(w[j] * inv);
    v = v < -127 ? -127 : (v > 127 ? 127 : v);
    q[j] = v & 0xff;
  }
  int p0 = q[0] | (q[1] << 8) | (q[2] << 16) | (q[3] << 24);
  int p1 = q[4] | (q[5] << 8) | (q[6] << 16) | (q[7] << 24);
  Wq[e*128 + lane*2]     = p0;
  Wq[e*128 + lane*2 + 1] = p1;
  if (lane == 0) sc[e] = m / (127.f * 127.f);
}

// ---------------- bf16 GEMM: C[m][n] = sum_k A[m][k]*Bt[n][k] -------------
__global__ __launch_bounds__(256) void gemm_bt_k(const u16* __restrict__ A,
                                                 const u16* __restrict__ Bt,
                                                 u16* __restrict__ C,
                                                 int do_tanh){
  __shared__ __align__(16) u16 As[128*32];
  __shared__ __align__(16) u16 Bs[128*32];
  int tid = threadIdx.x;
  int bm = blockIdx.x, bn = blockIdx.y;
  int wv = tid >> 6, lane = tid & 63;
  int wm = (wv & 1) * 64, wn = (wv >> 1) * 64;
  int m0 = lane & 15, quad = lane >> 4;
  f32x4 acc[4][4];
  #pragma unroll
  for (int i = 0; i < 4; i++)
    #pragma unroll
    for (int j = 0; j < 4; j++){
      f32x4 z = {0.f, 0.f, 0.f, 0.f};
      acc[i][j] = z;
    }
  const size_t arow = (size_t)bm * 128;
  const size_t brow = (size_t)bn * 128;
  for (int k0 = 0; k0 < D; k0 += 32){
    __syncthreads();
    #pragma unroll
    for (int i = 0; i < 2; i++){
      int c = tid + 256*i;
      int r = c >> 2, ko = (c & 3) * 8;
      ((int4*)As)[c] = *(const int4*)(A  + (arow + r) * D + k0 + ko);
      ((int4*)Bs)[c] = *(const int4*)(Bt + (brow + r) * D + k0 + ko);
    }
    __syncthreads();
    bf16x8 af[4], bfr[4];
    #pragma unroll
    for (int i = 0; i < 4; i++){
      af[i]  = *(const bf16x8*)(As + (wm + i*16 + m0) * 32 + quad*8);
      bfr[i] = *(const bf16x8*)(Bs + (wn + i*16 + m0) * 32 + quad*8);
    }
    #pragma unroll
    for (int i = 0; i < 4; i++)
      #pragma unroll
      for (int j = 0; j < 4; j++)
        acc[i][j] = __builtin_amdgcn_mfma_f32_16x16x32_bf16(af[i], bfr[j], acc[i][j], 0, 0, 0);
  }
  #pragma unroll
  for (int i = 0; i < 4; i++)
    #pragma unroll
    for (int j = 0; j < 4; j++)
      #pragma unroll
      for (int r = 0; r < 4; r++){
        size_t row = arow + wm + i*16 + quad*4 + r;
        int col = bn*128 + wn + j*16 + m0;
        float v = acc[i][j][r];
        if (do_tanh) v = tanhf(v);
        C[row * D + col] = f2bf(v);
      }
}

// ---------------- sequential LRU scan, one block per batch element --------
// K-split-4 VALU matvec. Lanes {m, m+16, m+32, m+48} of a wave form a quad;
// quad (wv, m) owns output dims base = wv*64 + m*4 + {0..3}. Each lane:
//   - holds weights for all 4 dims over ITS K-quarter (words q2*32..+31)
//     = 128 int regs (same total as before, different partitioning)
//   - reads only 128 B of h per step (8 ds_read_b128)  -> LDS return
//     traffic 256 KiB -> 64 KiB/step (the round-0 bottleneck, cut 4x)
//   - 2-stage integer __shfl_xor(16/32) reduce-transpose lands the exact
//     sum for dim base+q2 on this lane (int adds associative -> bit-identical)
// Writes H IN-PLACE over Nn (each lane touches only its own column e).
__global__ __launch_bounds__(512, 2) void lru_scan_k(u16* __restrict__ Nn,        // tanh(x@Wn), becomes H
                                                     const u16* __restrict__ Ff,  // x@Wif
                                                     const int* __restrict__ Wq,
                                                     const float* __restrict__ sc,
                                                     const float* __restrict__ bhf){
  int tid = threadIdx.x;
  int b = blockIdx.x;
  int wv = tid >> 6, l = tid & 63;
  int m  = l & 15;          // quad id within wave
  int q2 = l >> 4;          // position within quad = K-chunk = final dim offset
  int base_e = wv*64 + m*4;
  int e = base_e + q2;      // dim this lane finalizes

  // weights: 4 dims x my K-quarter (words q2*32 .. q2*32+31)
  int4 wq[4][8];
  #pragma unroll
  for (int j = 0; j < 4; j++){
    const int* wp = Wq + (size_t)(base_e + j) * 128 + q2*32;
    #pragma unroll
    for (int i = 0; i < 8; i++) wq[j][i] = ((const int4*)wp)[i];
  }
  float scale = sc[e];
  float bias  = bhf[e];

  __shared__ __align__(16) char hq[2][512];
  if (tid < 128) ((int*)hq[0])[tid] = 0;
  float h = 0.f;
  const size_t base = (size_t)b * TT * D + e;
  u16* np = Nn + base;
  const u16* fp = Ff + base;
  float nv  = bf2f(np[0]);
  float fvb = bf2f(fp[0]) + bias;
  __syncthreads();

  for (int t = 0; t < TT; t++){
    float nv_n = 0.f, fvb_n = 0.f;
    if (t < TT - 1){
      nv_n  = bf2f(np[(size_t)(t+1) * D]);
      fvb_n = bf2f(fp[(size_t)(t+1) * D]) + bias;
    }
    const char* hb = hq[t & 1] + q2*128;   // my 128-B quarter of h
    int p0 = 0, p1 = 0, p2 = 0, p3 = 0;    // partials for dims base_e+0..3
    #pragma unroll
    for (int i = 0; i < 8; i++){
      int4 a = ((const int4*)hb)[i];
      p0 = dot4i8(wq[0][i].x, a.x, p0); p0 = dot4i8(wq[0][i].y, a.y, p0);
      p0 = dot4i8(wq[0][i].z, a.z, p0); p0 = dot4i8(wq[0][i].w, a.w, p0);
      p1 = dot4i8(wq[1][i].x, a.x, p1); p1 = dot4i8(wq[1][i].y, a.y, p1);
      p1 = dot4i8(wq[1][i].z, a.z, p1); p1 = dot4i8(wq[1][i].w, a.w, p1);
      p2 = dot4i8(wq[2][i].x, a.x, p2); p2 = dot4i8(wq[2][i].y, a.y, p2);
      p2 = dot4i8(wq[2][i].z, a.z, p2); p2 = dot4i8(wq[2][i].w, a.w, p2);
      p3 = dot4i8(wq[3][i].x, a.x, p3); p3 = dot4i8(wq[3][i].y, a.y, p3);
      p3 = dot4i8(wq[3][i].z, a.z, p3); p3 = dot4i8(wq[3][i].w, a.w, p3);
    }
    // quad reduce-transpose: stage 1 over xor16 (flips q2 bit0) keeps dims
    // with bit0 == my bit0; stage 2 over xor32 (flips bit1) keeps dim q2.
    int b0 = q2 & 1, b1 = q2 >> 1;
    int send0 = b0 ? p0 : p1, keep0 = b0 ? p1 : p0;   // dims {0,1}
    int send1 = b0 ? p2 : p3, keep1 = b0 ? p3 : p2;   // dims {2,3}
    int z0 = keep0 + __shfl_xor(send0, 16);           // dim b0
    int z1 = keep1 + __shfl_xor(send1, 16);           // dim 2+b0
    int zs = b1 ? z0 : z1, zk = b1 ? z1 : z0;
    int z  = zk + __shfl_xor(zs, 32);                 // dim 2*b1+b0 = q2
    float arg = (float)z * scale + fvb;
    float g = 1.f / (1.f + __expf(-arg));
    h = h + g * (nv - h);
    np[(size_t)t * D] = f2bf(h);          // overwrite Nn with H
    int q = __float2int_rn(h * 127.f);
    q = q < -127 ? -127 : (q > 127 ? 127 : q);
    hq[(t+1) & 1][e] = (char)q;
    nv = nv_n; fvb = fvb_n;
    // raw barrier: drain LDS only (global h-store may stay in flight)
    asm volatile("s_waitcnt lgkmcnt(0)\n\ts_barrier" ::: "memory");
  }
}

// ---------------- final gate_cell, pass 1: lru -> (in-place over Nng) -----
__global__ __launch_bounds__(256) void final1_k(const u16* __restrict__ xn,
                                                u16* __restrict__ Nng,        // tanh(h1@gWn), becomes lru
                                                const u16* __restrict__ Ffg,  // h1@gWif
                                                const u16* __restrict__ Ghf,  // xn@gWhf
                                                const float* __restrict__ gbhf){
  size_t i = (size_t)blockIdx.x * 256 + threadIdx.x;
  int e = (int)(i & (D - 1));
  float xnv = bf2f(xn[i]);
  float nv  = bf2f(Nng[i]);
  float arg = bf2f(Ghf[i]) + gbhf[e] + bf2f(Ffg[i]);
  float g = 1.f / (1.f + __expf(-arg));
  float lru = xnv + g * (nv - xnv);
  Nng[i] = f2bf(lru);
}

// ---------------- final pass 2: out = lru + x (fp32) ----------------------
__global__ __launch_bounds__(256) void final2_k(const u16* __restrict__ lru,
                                                const float* __restrict__ x,
                                                float* __restrict__ out){
  size_t i = (size_t)blockIdx.x * 256 + threadIdx.x;
  out[i] = bf2f(lru[i]) + x[i];
}

extern "C" void kernel_launch(void* const* d_in, const int* in_sizes, int n_in,
                              void* d_out, int out_size, void* d_ws, size_t ws_size,
                              hipStream_t stream){
  const float* x      = (const float*)d_in[0];
  const float* gamma  = (const float*)d_in[1];
  const float* g_Wn   = (const float*)d_in[2];
  const float* g_Wif  = (const float*)d_in[3];
  const float* g_Whf  = (const float*)d_in[4];
  const float* g_bhf  = (const float*)d_in[5];
  const float* l0_Wn  = (const float*)d_in[6];
  const float* l0_Wif = (const float*)d_in[7];
  const float* l0_Whf = (const float*)d_in[8];
  const float* l0_bhf = (const float*)d_in[9];
  const float* l1_Wn  = (const float*)d_in[10];
  const float* l1_Wif = (const float*)d_in[11];
  const float* l1_Whf = (const float*)d_in[12];
  const float* l1_bhf = (const float*)d_in[13];
  float* out = (float*)d_out;

  // ---- plane layout: P0,P1 in ws; P2,P3 inside d_out (2 bf16 planes = 134MB)
  char* ws = (char*)d_ws;
  const size_t PLANE = (size_t)BT * D * 2;      // 67.1 MB bf16 plane
  u16* P0 = (u16*)(ws);                         // xn (live to the end)
  u16* P1 = (u16*)(ws + PLANE);                 // Nn0/H0, then Nn_g, then lru
  u16* P2 = (u16*)d_out;                        // Ff planes
  u16* P3 = P2 + (size_t)BT * D;                // Nn1/H1, then Ghf

  char* wb = ws + 2*PLANE;
  const size_t WSZ = (size_t)D * D * 2;         // 512 KB per transposed bf16 weight
  u16* T_l0Wn  = (u16*)(wb + 0*WSZ);
  u16* T_l0Wif = (u16*)(wb + 1*WSZ);
  u16* T_gWhf  = (u16*)(wb + 2*WSZ);
  u16* T_l1Wn  = (u16*)(wb + 3*WSZ);
  u16* T_l1Wif = (u16*)(wb + 4*WSZ);
  u16* T_gWn   = (u16*)(wb + 5*WSZ);
  u16* T_gWif  = (u16*)(wb + 6*WSZ);
  int*   Wq0 = (int*)  (wb + 7*WSZ);
  int*   Wq1 = (int*)  (wb + 7*WSZ + (size_t)D*D);
  float* sc0 = (float*)(wb + 7*WSZ + 2*(size_t)D*D);
  float* sc1 = (float*)(wb + 7*WSZ + 2*(size_t)D*D + D*4);

  dim3 tb(256), tg(16, 16);
  // weight prep (tiny)
  transpose_k<<<tg, tb, 0, stream>>>(l0_Wn,  T_l0Wn);
  transpose_k<<<tg, tb, 0, stream>>>(l0_Wif, T_l0Wif);
  transpose_k<<<tg, tb, 0, stream>>>(g_Whf,  T_gWhf);
  transpose_k<<<tg, tb, 0, stream>>>(l1_Wn,  T_l1Wn);
  transpose_k<<<tg, tb, 0, stream>>>(l1_Wif, T_l1Wif);
  transpose_k<<<tg, tb, 0, stream>>>(g_Wn,   T_gWn);
  transpose_k<<<tg, tb, 0, stream>>>(g_Wif,  T_gWif);
  quant_col_k<<<512, 64, 0, stream>>>(l0_Whf, Wq0, sc0);
  quant_col_k<<<512, 64, 0, stream>>>(l1_Whf, Wq1, sc1);

  rmsnorm_k<<<BT, 256, 0, stream>>>(x, gamma, P0);

  dim3 gg(BT/128, D/128);
  // layer 0
  gemm_bt_k<<<gg, tb, 0, stream>>>(P0, T_l0Wn,  P1, 1);   // Nn0
  gemm_bt_k<<<gg, tb, 0, stream>>>(P0, T_l0Wif, P2, 0);   // Ff0
  lru_scan_k<<<BATCH, 512, 0, stream>>>(P1, P2, Wq0, sc0, l0_bhf);  // H0 -> P1
  // layer 1
  gemm_bt_k<<<gg, tb, 0, stream>>>(P1, T_l1Wn,  P3, 1);   // Nn1
  gemm_bt_k<<<gg, tb, 0, stream>>>(P1, T_l1Wif, P2, 0);   // Ff1
  lru_scan_k<<<BATCH, 512, 0, stream>>>(P3, P2, Wq1, sc1, l1_bhf);  // H1 -> P3
  // gate cell projections (H0 dead -> P1, Ff1 dead -> P2)
  gemm_bt_k<<<gg, tb, 0, stream>>>(P3, T_gWn,  P1, 1);    // Nn_g
  gemm_bt_k<<<gg, tb, 0, stream>>>(P3, T_gWif, P2, 0);    // Ff_g
  gemm_bt_k<<<gg, tb, 0, stream>>>(P0, T_gWhf, P3, 0);    // Ghf (H1 dead)

  final1_k<<<BT*D/256, 256, 0, stream>>>(P0, P1, P2, P3, g_bhf);  // lru -> P1
  final2_k<<<BT*D/256, 256, 0, stream>>>(P1, x, out);
}